// Round 1
// 775.437 us; speedup vs baseline: 1.0553x; 1.0553x over previous
//
#include <hip/hip_runtime.h>
#include <math.h>

#define NNODES 1048576
#define NSEG   8192
#define DIN    128
#define DH     64

typedef __bf16 bf16x8 __attribute__((ext_vector_type(8)));
typedef __bf16 bf16x4 __attribute__((ext_vector_type(4)));
typedef float  f32x4  __attribute__((ext_vector_type(4)));

// ---------------- prep kernel 1: node -> segment id + zero tokens ----------------
__global__ void seg_fill_kernel(const int* __restrict__ offset, int* __restrict__ seg_id,
                                float* __restrict__ tokens) {
    int s = blockIdx.x;
    tokens[s * DH + (int)threadIdx.x] = 0.f;        // blockDim = 64 -> zeroes this segment's row
    int start = offset[s], end = offset[s + 1];
    for (int i = start + (int)threadIdx.x; i < end; i += (int)blockDim.x) seg_id[i] = s;
}

// ---------------- prep kernel 2: fold attention (seq len 1 => attn == 1, ctx == v) ----
__global__ void fold_kernel(const float* __restrict__ in_proj_w, const float* __restrict__ in_proj_b,
                            const float* __restrict__ out_w, const float* __restrict__ out_b,
                            float* __restrict__ Mt, float* __restrict__ bfold) {
    int t = blockIdx.x * blockDim.x + threadIdx.x;   // 0..4095 over 16 blocks x 256
    int i = t >> 6, j = t & 63;
    const float* Wv = in_proj_w + 2 * DH * DH;       // third 64-row block
    float sum = 0.f;
#pragma unroll 8
    for (int k = 0; k < DH; ++k) sum += out_w[i * DH + k] * Wv[k * DH + j];
    Mt[j * DH + i] = sum;
    if (t < DH) {
        const float* bv = in_proj_b + 2 * DH;
        float s2 = out_b[t];
#pragma unroll 8
        for (int k = 0; k < DH; ++k) s2 += out_w[t * DH + k] * bv[k];
        bfold[t] = s2;
    }
}

// async global->LDS: one call stages 1 KB (64 lanes x 16 B), 8 calls = one 16-node subtile (8 KB)
__device__ __forceinline__ void stage16x8(const char* src_lane, float* lds_base) {
#pragma unroll
    for (int i = 0; i < 8; ++i)
        __builtin_amdgcn_global_load_lds(
            (const __attribute__((address_space(1))) void*)(src_lane + i * 64),
            (__attribute__((address_space(3))) void*)((char*)lds_base + i * 1024),
            16, 0, 0);
}

// ---------------- main fused kernel: 2-layer MLP (bf16 MFMA) + segment sum ----------
// grid 4096 x 256; each wave owns 64 nodes = 4 subtiles of 16, pipelined 2-deep through
// its private LDS staging buffers (global_load_lds, counted vmcnt waits, no barriers).
// LDS x layout is 16B-unit transposed: slot = u*16 + node (u = 16B unit within the row),
// realized by permuting the per-lane GLOBAL source (dest must stay linear). Frag reads
// (b128) then spread 8 lanes per 4-bank group = conflict-free-minimal.
// Layer 1 uses swapped MFMA operands (D = W1 . x^T): col=node, row=h-dim, so the h1
// transpose is 4 packed ds_write_b64 per lane instead of 16 ds_write_b16.
__launch_bounds__(256, 2)
__global__ void mlp_seg_kernel(const float* __restrict__ x, const int* __restrict__ seg_id,
                               const float* __restrict__ W1, const float* __restrict__ b1,
                               const float* __restrict__ W2, const float* __restrict__ b2,
                               float* __restrict__ tokens) {
    const int tid  = threadIdx.x;
    const int w    = tid >> 6;
    const int lane = tid & 63;
    const int quad = lane >> 4;
    const int col  = lane & 15;

    __shared__ __align__(16) float  xstage[4][2][2048];   // 64 KB: per-wave double-buffered x subtile
    __shared__ __align__(16) __bf16 h1w[4][16][72];       // 9 KB: per-wave h1, node-major, stride 72 (16B-aligned rows)

    // ---- stage weight fragments into registers (once per block) ----
    // A-frag and B-frag lane layouts coincide: lane&15 = row/col, k = kt*32 + quad*8 + j
    bf16x8 w1f[4][4];
#pragma unroll
    for (int nt = 0; nt < 4; ++nt)
#pragma unroll
        for (int kt = 0; kt < 4; ++kt) {
            const float* wp = W1 + (nt * 16 + col) * DIN + kt * 32 + quad * 8;
#pragma unroll
            for (int j = 0; j < 8; ++j) w1f[nt][kt][j] = (__bf16)wp[j];
        }
    bf16x8 w2f[4][2];
#pragma unroll
    for (int nt = 0; nt < 4; ++nt)
#pragma unroll
        for (int kt = 0; kt < 2; ++kt) {
            const float* wp = W2 + (nt * 16 + col) * DH + kt * 32 + quad * 8;
#pragma unroll
            for (int j = 0; j < 8; ++j) w2f[nt][kt][j] = (__bf16)wp[j];
        }
    float4 b1q[4];   // layer-1 bias now varies along rows (h-dim): 4 consecutive per (nt,quad)
    float  b2v[4];
#pragma unroll
    for (int nt = 0; nt < 4; ++nt) {
        b1q[nt] = *(const float4*)(b1 + nt * 16 + quad * 4);
        b2v[nt] = b2[nt * 16 + col];
    }

    const int nb0 = blockIdx.x * 256 + w * 64;
    const int seg_all = seg_id[nb0 + lane];          // one load covers all 4 subtiles

    // per-lane source: row (nb0+col), 16B unit (quad + 4i) -> affine in issue index i
    const char* src0 = (const char*)(x + (size_t)(nb0 + col) * DIN + quad * 4);

    float* sbuf0 = &xstage[w][0][0];
    float* sbuf1 = &xstage[w][1][0];
    stage16x8(src0,        sbuf0);                   // subtile 0
    stage16x8(src0 + 8192, sbuf1);                   // subtile 1

#pragma unroll
    for (int t = 0; t < 4; ++t) {
        // wait for subtile t's 8 loads; keep the newest 8 (subtile t+1) in flight
        if (t < 3) asm volatile("s_waitcnt vmcnt(8)" ::: "memory");
        else       asm volatile("s_waitcnt vmcnt(0)" ::: "memory");
        __builtin_amdgcn_sched_barrier(0);

        const float4* sb = (const float4*)((t & 1) ? sbuf1 : sbuf0);

        // ---- A-frags from transposed LDS: slot (kt*8 + quad*2 + half)*16 + col ----
        bf16x8 a[4];
#pragma unroll
        for (int kt = 0; kt < 4; ++kt) {
            float4 u  = sb[(kt * 8 + quad * 2) * 16 + col];
            float4 v2 = sb[(kt * 8 + quad * 2 + 1) * 16 + col];
            a[kt][0] = (__bf16)u.x;  a[kt][1] = (__bf16)u.y;
            a[kt][2] = (__bf16)u.z;  a[kt][3] = (__bf16)u.w;
            a[kt][4] = (__bf16)v2.x; a[kt][5] = (__bf16)v2.y;
            a[kt][6] = (__bf16)v2.z; a[kt][7] = (__bf16)v2.w;
        }

        // ---- layer 1, swapped operands: D = W1tile(16h x 128) . x^T(128 x 16n) ----
        // C-layout: col = lane&15 = node, row = quad*4+r = h-dim (within tile nt)
        f32x4 acc1[4];
#pragma unroll
        for (int nt = 0; nt < 4; ++nt) acc1[nt] = (f32x4){0.f, 0.f, 0.f, 0.f};
#pragma unroll
        for (int kt = 0; kt < 4; ++kt)
#pragma unroll
            for (int nt = 0; nt < 4; ++nt)
                acc1[nt] = __builtin_amdgcn_mfma_f32_16x16x32_bf16(w1f[nt][kt], a[kt], acc1[nt], 0, 0, 0);

        // bias + relu; lane holds 4 consecutive h-dims per nt -> one packed b64 write
#pragma unroll
        for (int nt = 0; nt < 4; ++nt) {
            bf16x4 hw;
#pragma unroll
            for (int r = 0; r < 4; ++r)
                hw[r] = (__bf16)fmaxf(acc1[nt][r] + ((const float*)&b1q[nt])[r], 0.f);
            *(bf16x4*)&h1w[w][col][nt * 16 + quad * 4] = hw;
        }

        // layer-2 A-frags: h1[node][kt*32 + quad*8 ..+7], 16B aligned (stride 144 B)
        bf16x8 a2[2];
#pragma unroll
        for (int kt = 0; kt < 2; ++kt)
            a2[kt] = *(const bf16x8*)&h1w[w][col][kt * 32 + quad * 8];

        // ---- layer 2 (standard): col = h-dim, row = node — same as before ----
        f32x4 acc2[4];
#pragma unroll
        for (int nt = 0; nt < 4; ++nt) acc2[nt] = (f32x4){0.f, 0.f, 0.f, 0.f};
#pragma unroll
        for (int kt = 0; kt < 2; ++kt)
#pragma unroll
            for (int nt = 0; nt < 4; ++nt)
                acc2[nt] = __builtin_amdgcn_mfma_f32_16x16x32_bf16(a2[kt], w2f[nt][kt], acc2[nt], 0, 0, 0);

        float hv[4][4];
#pragma unroll
        for (int nt = 0; nt < 4; ++nt)
#pragma unroll
            for (int r = 0; r < 4; ++r)
                hv[nt][r] = fmaxf(acc2[nt][r] + b2v[nt], 0.f);

        // ---- segmented sum over the 16 nodes ----
        int s0 = __shfl(seg_all, t * 16);
        int s1 = __shfl(seg_all, t * 16 + 15);
        if (s0 == s1) {
            float p[4];
#pragma unroll
            for (int nt = 0; nt < 4; ++nt) {
                p[nt] = hv[nt][0] + hv[nt][1] + hv[nt][2] + hv[nt][3];
                p[nt] += __shfl_xor(p[nt], 16);
                p[nt] += __shfl_xor(p[nt], 32);
            }
            float val = (quad == 0) ? p[0] : (quad == 1) ? p[1] : (quad == 2) ? p[2] : p[3];
            atomicAdd(&tokens[s0 * DH + quad * 16 + col], val);
        } else {
            int segs[4];
#pragma unroll
            for (int r = 0; r < 4; ++r) segs[r] = __shfl(seg_all, t * 16 + quad * 4 + r);
#pragma unroll
            for (int nt = 0; nt < 4; ++nt)
#pragma unroll
                for (int r = 0; r < 4; ++r)
                    atomicAdd(&tokens[segs[r] * DH + nt * 16 + col], hv[nt][r]);
        }

        // issue next-next subtile's stage AFTER all reads of this buffer completed
        __builtin_amdgcn_sched_barrier(0);
        if (t == 0) stage16x8(src0 + 2 * 8192, sbuf0);
        if (t == 1) stage16x8(src0 + 3 * 8192, sbuf1);
        __builtin_amdgcn_sched_barrier(0);
    }
}

// ---------------- final projection: out[s] = tokens[s] @ M^T + bfold ----------------
__global__ void out_kernel(const float* __restrict__ tokens, const float* __restrict__ Mt,
                           const float* __restrict__ bfold, float* __restrict__ out) {
    __shared__ float mt[DH * DH];
    __shared__ float bf[DH];
    for (int i = threadIdx.x; i < DH * DH; i += 256) mt[i] = Mt[i];
    if (threadIdx.x < DH) bf[threadIdx.x] = bfold[threadIdx.x];
    __syncthreads();
    int sl = threadIdx.x >> 6;
    int d  = threadIdx.x & 63;
    int s  = blockIdx.x * 4 + sl;
    const float* trow = tokens + s * DH;
    float sum = bf[d];
#pragma unroll 16
    for (int k = 0; k < DH; ++k) sum += trow[k] * mt[k * DH + d];  // mt read conflict-free
    out[s * DH + d] = sum;
}

extern "C" void kernel_launch(void* const* d_in, const int* in_sizes, int n_in,
                              void* d_out, int out_size, void* d_ws, size_t ws_size,
                              hipStream_t stream) {
    const float* x         = (const float*)d_in[0];
    const int*   offset    = (const int*)d_in[1];
    const float* W1        = (const float*)d_in[2];
    const float* b1        = (const float*)d_in[3];
    const float* W2        = (const float*)d_in[4];
    const float* b2        = (const float*)d_in[5];
    const float* in_proj_w = (const float*)d_in[6];
    const float* in_proj_b = (const float*)d_in[7];
    const float* out_w     = (const float*)d_in[8];
    const float* out_b     = (const float*)d_in[9];
    float* out = (float*)d_out;

    char* ws = (char*)d_ws;
    float* tokens = (float*)ws;                                   // 8192*64*4 = 2 MB
    int*   seg_id = (int*)(ws + (size_t)NSEG * DH * 4);           // 4 MB
    float* Mt     = (float*)(ws + (size_t)NSEG * DH * 4 + (size_t)NNODES * 4); // 16 KB
    float* bfold  = Mt + DH * DH;                                 // 256 B

    seg_fill_kernel<<<NSEG, 64, 0, stream>>>(offset, seg_id, tokens);
    fold_kernel<<<16, 256, 0, stream>>>(in_proj_w, in_proj_b, out_w, out_b, Mt, bfold);
    mlp_seg_kernel<<<NNODES / 256, 256, 0, stream>>>(x, seg_id, W1, b1, W2, b2, tokens);
    out_kernel<<<NSEG / 4, 256, 0, stream>>>(tokens, Mt, bfold, out);
}